// Round 1
// baseline (360.476 us; speedup 1.0000x reference)
//
#include <hip/hip_runtime.h>
#include <hip/hip_fp16.h>
#include <cstdint>
#include <cstddef>

#define NB   4096   // batch
#define ND   128    // feature dim
#define OUTW 16384  // 4*NB output row width

typedef _Float16 f16;
typedef __attribute__((ext_vector_type(2))) _Float16 f16x2;
typedef __attribute__((ext_vector_type(8))) _Float16 f16x8;
typedef __attribute__((ext_vector_type(4))) float   f32x4;

// ---------------------------------------------------------------------------
// Kernel 1: l2-normalize z1,z2 rows and cast to f16.  ab = [a(4096x128) | b]
// One wave per row; lane holds float2.
// ---------------------------------------------------------------------------
__global__ __launch_bounds__(256) void nrm_kernel(const float* __restrict__ z1,
                                                  const float* __restrict__ z2,
                                                  f16* __restrict__ ab) {
  int row  = blockIdx.x * 4 + (threadIdx.x >> 6);
  int lane = threadIdx.x & 63;
  const float* src = (row < NB) ? (z1 + (size_t)row * ND)
                                : (z2 + (size_t)(row - NB) * ND);
  float2 v = ((const float2*)src)[lane];
  float ss = v.x * v.x + v.y * v.y;
#pragma unroll
  for (int off = 32; off; off >>= 1) ss += __shfl_xor(ss, off);
  float r = rsqrtf(fmaxf(ss, 1e-12f));
  f16x2 h;
  h.x = (f16)(v.x * r);
  h.y = (f16)(v.y * r);
  ((f16x2*)(ab + (size_t)row * ND))[lane] = h;
}

// ---------------------------------------------------------------------------
// GEMM+softmax passes. Logical rows r in [0,8192): r<4096 -> part1 (query=a),
// else part2 (query=b). Logical cols c in [0,8192): first half vs "other"
// matrix, second half vs own matrix (diag masked).
// Tile: 128 rows x 128 cols, K=128 in one LDS stage. 256 thr = 4 waves (2x2),
// each wave 64x64 via 4x4 grid of 16x16x32 f16 MFMAs.
// WRITE=false: accumulate exp(logit-10) row sums via atomicAdd.
// WRITE=true : out = exp(logit-10) / rowsum.
// ---------------------------------------------------------------------------
template <bool WRITE>
__global__ __launch_bounds__(256) void pass_kernel(const f16* __restrict__ ab,
                                                   float* __restrict__ rowsum,
                                                   float* __restrict__ out) {
  __shared__ f16 As[128 * ND];   // 32 KB, row-major, 16B-octets XOR-swizzled
  __shared__ f16 Bs[128 * ND];   // 32 KB
  __shared__ float rs[128];

  const int t    = threadIdx.x;
  const int wave = t >> 6;
  const int lane = t & 63;
  const int rt   = blockIdx.y;          // 0..63 (row tile)
  const int ct   = blockIdx.x;          // 0..63 (col tile)
  const int type = rt >> 5;             // 0 = part1, 1 = part2
  const int r0   = (rt & 31) * 128;     // query row base within [0,4096)
  const int c0l  = ct * 128;            // logical col base, 0..8191
  const int h2   = (c0l >= NB) ? 1 : 0; // second half -> diag-masked block
  const int c0   = c0l & (NB - 1);
  const f16* Q = ab + (size_t)type * NB * ND;
  const f16* K = ab + (size_t)(h2 ^ type ^ 1) * NB * ND;

  // ---- stage tiles: global -> LDS, 16B per lane, lane-contiguous dest.
  // LDS granule g of row m holds global octet (g ^ (m&15))  (bank-conflict fix
  // applied on the GLOBAL side so global_load_lds dest stays contiguous).
  {
    int sub = t >> 4;  // 0..15
    int oct = t & 15;
#pragma unroll
    for (int i = 0; i < 8; ++i) {
      int rowl = i * 16 + sub;
      int goct = oct ^ (rowl & 15);
      const f16* ga = Q + (size_t)(r0 + rowl) * ND + goct * 8;
      const f16* gb = K + (size_t)(c0 + rowl) * ND + goct * 8;
      __builtin_amdgcn_global_load_lds(
          (const __attribute__((address_space(1))) void*)ga,
          (__attribute__((address_space(3))) void*)(As + rowl * ND + oct * 8),
          16, 0, 0);
      __builtin_amdgcn_global_load_lds(
          (const __attribute__((address_space(1))) void*)gb,
          (__attribute__((address_space(3))) void*)(Bs + rowl * ND + oct * 8),
          16, 0, 0);
    }
  }
  if (WRITE) {
    if (t < 128) rs[t] = 1.0f / rowsum[rt * 128 + t];
  }
  __syncthreads();

  const int wr   = wave >> 1;
  const int wc   = wave & 1;
  const int quad = lane >> 4;
  const int l16  = lane & 15;

  f32x4 acc[4][4] = {};
#pragma unroll
  for (int ks = 0; ks < 4; ++ks) {
    f16x8 af[4], bf[4];
    int oct = ks * 4 + quad;
    int sw  = (oct ^ l16) * 8;  // row&15 == l16 for every fragment row
#pragma unroll
    for (int mi = 0; mi < 4; ++mi)
      af[mi] = *(const f16x8*)(As + (wr * 64 + mi * 16 + l16) * ND + sw);
#pragma unroll
    for (int ni = 0; ni < 4; ++ni)
      bf[ni] = *(const f16x8*)(Bs + (wc * 64 + ni * 16 + l16) * ND + sw);
#pragma unroll
    for (int mi = 0; mi < 4; ++mi)
#pragma unroll
      for (int ni = 0; ni < 4; ++ni)
        acc[mi][ni] = __builtin_amdgcn_mfma_f32_16x16x32_f16(af[mi], bf[ni],
                                                             acc[mi][ni], 0, 0, 0);
  }

  if (WRITE) {
#pragma unroll
    for (int mi = 0; mi < 4; ++mi) {
#pragma unroll
      for (int ni = 0; ni < 4; ++ni) {
        int col_l = wc * 64 + ni * 16 + l16;
        int cg    = c0l + col_l;                 // logical col 0..8191
        int rbase = wr * 64 + mi * 16 + quad * 4;
#pragma unroll
        for (int r = 0; r < 4; ++r) {
          int row_l = rbase + r;
          int rg    = r0 + row_l;                // 0..4095 batch index
          float e = __expf(fmaf(acc[mi][ni][r], 10.0f, -10.0f));
          if (h2 && (cg - NB) == rg) e = 0.0f;   // masked diagonal
          out[(size_t)rg * OUTW + (size_t)type * 8192 + cg] = e * rs[row_l];
        }
      }
    }
  } else {
#pragma unroll
    for (int mi = 0; mi < 4; ++mi) {
      float ps[4] = {0.f, 0.f, 0.f, 0.f};
#pragma unroll
      for (int ni = 0; ni < 4; ++ni) {
        int col_l = wc * 64 + ni * 16 + l16;
        int cg    = c0l + col_l;
        int rbase = wr * 64 + mi * 16 + quad * 4;
#pragma unroll
        for (int r = 0; r < 4; ++r) {
          int rg = r0 + rbase + r;
          float e = __expf(fmaf(acc[mi][ni][r], 10.0f, -10.0f));
          if (h2 && (cg - NB) == rg) e = 0.0f;
          ps[r] += e;
        }
      }
#pragma unroll
      for (int r = 0; r < 4; ++r) {
        float v = ps[r];
#pragma unroll
        for (int off = 1; off < 16; off <<= 1) v += __shfl_xor(v, off);
        if (l16 == 0) {
          int row_l = wr * 64 + mi * 16 + quad * 4 + r;
          atomicAdd(&rowsum[rt * 128 + row_l], v);
        }
      }
    }
  }
}

// ---------------------------------------------------------------------------
extern "C" void kernel_launch(void* const* d_in, const int* in_sizes, int n_in,
                              void* d_out, int out_size, void* d_ws, size_t ws_size,
                              hipStream_t stream) {
  const float* z1 = (const float*)d_in[0];
  const float* z2 = (const float*)d_in[1];
  float* out = (float*)d_out;

  f16* ab = (f16*)d_ws;                                   // 8192x128 f16 = 2 MB
  float* rowsum = (float*)((char*)d_ws + (size_t)8192 * ND * sizeof(f16)); // 32 KB

  nrm_kernel<<<2048, 256, 0, stream>>>(z1, z2, ab);
  hipMemsetAsync(rowsum, 0, 8192 * sizeof(float), stream);
  dim3 grid(64, 64);
  pass_kernel<false><<<grid, 256, 0, stream>>>(ab, rowsum, out);
  pass_kernel<true><<<grid, 256, 0, stream>>>(ab, rowsum, out);
}

// Round 2
// 356.743 us; speedup vs baseline: 1.0105x; 1.0105x over previous
//
#include <hip/hip_runtime.h>
#include <hip/hip_fp16.h>
#include <cstdint>
#include <cstddef>

#define NB   4096   // batch
#define ND   128    // feature dim
#define OUTW 16384  // 4*NB output row width

// 10 * log2(e): logits = cos/T = 10*acc; exp(10a-10) = 2^(K2*a - K2)
#define K2   14.4269504088896341f

typedef _Float16 f16;
typedef __attribute__((ext_vector_type(2))) _Float16 f16x2;
typedef __attribute__((ext_vector_type(8))) _Float16 f16x8;
typedef __attribute__((ext_vector_type(4))) float   f32x4;

// ---------------------------------------------------------------------------
// Kernel 1: l2-normalize z1,z2 rows, cast to f16; also zero rowsum (8192 f32)
// so no separate memset launch is needed. One wave per row.
// ---------------------------------------------------------------------------
__global__ __launch_bounds__(256) void nrm_kernel(const float* __restrict__ z1,
                                                  const float* __restrict__ z2,
                                                  f16* __restrict__ ab,
                                                  float* __restrict__ rowsum) {
  if (threadIdx.x < 4) rowsum[blockIdx.x * 4 + threadIdx.x] = 0.0f;
  int row  = blockIdx.x * 4 + (threadIdx.x >> 6);
  int lane = threadIdx.x & 63;
  const float* src = (row < NB) ? (z1 + (size_t)row * ND)
                                : (z2 + (size_t)(row - NB) * ND);
  float2 v = ((const float2*)src)[lane];
  float ss = v.x * v.x + v.y * v.y;
#pragma unroll
  for (int off = 32; off; off >>= 1) ss += __shfl_xor(ss, off);
  float r = rsqrtf(fmaxf(ss, 1e-12f));
  f16x2 h;
  h.x = (f16)(v.x * r);
  h.y = (f16)(v.y * r);
  ((f16x2*)(ab + (size_t)row * ND))[lane] = h;
}

// ---------------------------------------------------------------------------
// GEMM+softmax passes (see R0 notes). 128x128 tile, K=128 single LDS stage,
// 4 waves of 64x64 via 4x4 16x16x32 f16 MFMAs. XOR-swizzled octets so
// global_load_lds dest stays lane-contiguous AND ds_read_b128 is ~conflict-free.
// WRITE=false: rowsum += exp2(K2*acc - K2)  (fixed max=10 is safe: |logit|<=10)
// WRITE=true : out = exp2(K2*acc + c_row),  c_row = -log2(sum) - K2
// Diagonal (-1e9 mask in ref => prob 0) zeroed only in the 64 blocks that
// contain it (h2 && c0==r0) -- block-uniform flag, not per-element in general.
// ---------------------------------------------------------------------------
template <bool WRITE>
__global__ __launch_bounds__(256) void pass_kernel(const f16* __restrict__ ab,
                                                   float* __restrict__ rowsum,
                                                   float* __restrict__ out) {
  __shared__ f16 As[128 * ND];   // 32 KB
  __shared__ f16 Bs[128 * ND];   // 32 KB
  __shared__ float cs[128];

  const int t    = threadIdx.x;
  const int wave = t >> 6;
  const int lane = t & 63;
  const int rt   = blockIdx.y;          // 0..63 (row tile)
  const int ct   = blockIdx.x;          // 0..63 (col tile)
  const int type = rt >> 5;             // 0 = part1 (query a), 1 = part2 (query b)
  const int r0   = (rt & 31) * 128;     // query row base within [0,4096)
  const int c0l  = ct * 128;            // logical col base, 0..8191
  const int h2   = (c0l >= NB) ? 1 : 0; // second half -> own-matrix block
  const int c0   = c0l & (NB - 1);
  const bool diag = h2 && (c0 == r0);   // only these blocks hold diagonal elems
  const f16* Q = ab + (size_t)type * NB * ND;
  const f16* K = ab + (size_t)(h2 ^ type ^ 1) * NB * ND;

  // ---- stage tiles: global -> LDS, 16B/lane, lane-contiguous LDS dest.
  // LDS granule g of row m holds global octet g ^ (m&15).
  {
    int sub = t >> 4;  // 0..15
    int oct = t & 15;
#pragma unroll
    for (int i = 0; i < 8; ++i) {
      int rowl = i * 16 + sub;
      int goct = oct ^ (rowl & 15);
      const f16* ga = Q + (size_t)(r0 + rowl) * ND + goct * 8;
      const f16* gb = K + (size_t)(c0 + rowl) * ND + goct * 8;
      __builtin_amdgcn_global_load_lds(
          (const __attribute__((address_space(1))) void*)ga,
          (__attribute__((address_space(3))) void*)(As + rowl * ND + oct * 8),
          16, 0, 0);
      __builtin_amdgcn_global_load_lds(
          (const __attribute__((address_space(1))) void*)gb,
          (__attribute__((address_space(3))) void*)(Bs + rowl * ND + oct * 8),
          16, 0, 0);
    }
  }
  if (WRITE) {
    if (t < 128) {
      float s = rowsum[rt * 128 + t];
      cs[t] = -__log2f(s) - K2;
    }
  }
  __syncthreads();

  const int wr   = wave >> 1;
  const int wc   = wave & 1;
  const int quad = lane >> 4;
  const int l16  = lane & 15;

  f32x4 acc[4][4] = {};
#pragma unroll
  for (int ks = 0; ks < 4; ++ks) {
    f16x8 af[4], bf[4];
    int oct = ks * 4 + quad;
    int sw  = (oct ^ l16) * 8;
#pragma unroll
    for (int mi = 0; mi < 4; ++mi)
      af[mi] = *(const f16x8*)(As + (wr * 64 + mi * 16 + l16) * ND + sw);
#pragma unroll
    for (int ni = 0; ni < 4; ++ni)
      bf[ni] = *(const f16x8*)(Bs + (wc * 64 + ni * 16 + l16) * ND + sw);
#pragma unroll
    for (int mi = 0; mi < 4; ++mi)
#pragma unroll
      for (int ni = 0; ni < 4; ++ni)
        acc[mi][ni] = __builtin_amdgcn_mfma_f32_16x16x32_f16(af[mi], bf[ni],
                                                             acc[mi][ni], 0, 0, 0);
  }

  if (WRITE) {
    // c_row for this lane's 16 rows: 4 per mi, consecutive -> float4 LDS reads
    float4 cf[4];
#pragma unroll
    for (int mi = 0; mi < 4; ++mi)
      cf[mi] = *(const float4*)&cs[wr * 64 + mi * 16 + quad * 4];
#pragma unroll
    for (int mi = 0; mi < 4; ++mi) {
#pragma unroll
      for (int ni = 0; ni < 4; ++ni) {
        int col_l = wc * 64 + ni * 16 + l16;
        int cg    = c0l + col_l;
        int rbase = wr * 64 + mi * 16 + quad * 4;
        const float* cp = &cf[mi].x;
#pragma unroll
        for (int r = 0; r < 4; ++r) {
          int row_l = rbase + r;
          int rg    = r0 + row_l;
          float e = __builtin_amdgcn_exp2f(fmaf(acc[mi][ni][r], K2, cp[r]));
          if (diag) { if (col_l == row_l) e = 0.0f; }
          out[(size_t)rg * OUTW + (size_t)type * 8192 + cg] = e;
        }
      }
    }
  } else {
#pragma unroll
    for (int mi = 0; mi < 4; ++mi) {
      float ps[4] = {0.f, 0.f, 0.f, 0.f};
#pragma unroll
      for (int ni = 0; ni < 4; ++ni) {
        int col_l = wc * 64 + ni * 16 + l16;
        int rbase = wr * 64 + mi * 16 + quad * 4;
#pragma unroll
        for (int r = 0; r < 4; ++r) {
          float e = __builtin_amdgcn_exp2f(fmaf(acc[mi][ni][r], K2, -K2));
          if (diag) { if (col_l == rbase + r) e = 0.0f; }
          ps[r] += e;
        }
      }
#pragma unroll
      for (int r = 0; r < 4; ++r) {
        float v = ps[r];
#pragma unroll
        for (int off = 1; off < 16; off <<= 1) v += __shfl_xor(v, off);
        if (l16 == 0) {
          int row_l = wr * 64 + mi * 16 + quad * 4 + r;
          atomicAdd(&rowsum[rt * 128 + row_l], v);
        }
      }
    }
  }
}

// ---------------------------------------------------------------------------
extern "C" void kernel_launch(void* const* d_in, const int* in_sizes, int n_in,
                              void* d_out, int out_size, void* d_ws, size_t ws_size,
                              hipStream_t stream) {
  const float* z1 = (const float*)d_in[0];
  const float* z2 = (const float*)d_in[1];
  float* out = (float*)d_out;

  f16* ab = (f16*)d_ws;                                   // 8192x128 f16 = 2 MB
  float* rowsum = (float*)((char*)d_ws + (size_t)8192 * ND * sizeof(f16)); // 32 KB

  nrm_kernel<<<2048, 256, 0, stream>>>(z1, z2, ab, rowsum);
  dim3 grid(64, 64);
  pass_kernel<false><<<grid, 256, 0, stream>>>(ab, rowsum, out);
  pass_kernel<true><<<grid, 256, 0, stream>>>(ab, rowsum, out);
}

// Round 3
// 305.522 us; speedup vs baseline: 1.1799x; 1.1676x over previous
//
#include <hip/hip_runtime.h>
#include <hip/hip_fp16.h>
#include <cstdint>
#include <cstddef>

#define NB   4096   // batch
#define ND   128    // feature dim
#define OUTW 16384  // 4*NB output row width
#define CG   16     // col groups (blockIdx.x); each covers 8192/CG logical cols
#define IT   (8192 / CG / 64)   // 64-col tiles per block = 8

// 10 * log2(e): logits = cos/T = 10*acc; exp(10a-10) = 2^(K2*a - K2)
#define K2   14.4269504088896341f

typedef _Float16 f16;
typedef __attribute__((ext_vector_type(2))) _Float16 f16x2;
typedef __attribute__((ext_vector_type(8))) _Float16 f16x8;
typedef __attribute__((ext_vector_type(4))) float   f32x4;

// ---------------------------------------------------------------------------
// Kernel 1: l2-normalize z1,z2 rows, cast to f16; also zero rowsum (8192 f32).
// One wave per row.
// ---------------------------------------------------------------------------
__global__ __launch_bounds__(256) void nrm_kernel(const float* __restrict__ z1,
                                                  const float* __restrict__ z2,
                                                  f16* __restrict__ ab,
                                                  float* __restrict__ rowsum) {
  if (threadIdx.x < 4) rowsum[blockIdx.x * 4 + threadIdx.x] = 0.0f;
  int row  = blockIdx.x * 4 + (threadIdx.x >> 6);
  int lane = threadIdx.x & 63;
  const float* src = (row < NB) ? (z1 + (size_t)row * ND)
                                : (z2 + (size_t)(row - NB) * ND);
  float2 v = ((const float2*)src)[lane];
  float ss = v.x * v.x + v.y * v.y;
#pragma unroll
  for (int off = 32; off; off >>= 1) ss += __shfl_xor(ss, off);
  float r = rsqrtf(fmaxf(ss, 1e-12f));
  f16x2 h;
  h.x = (f16)(v.x * r);
  h.y = (f16)(v.y * r);
  ((f16x2*)(ab + (size_t)row * ND))[lane] = h;
}

// ---------------------------------------------------------------------------
// Streaming GEMM+softmax pass.
// Block = 128-row strip (rt=blockIdx.y: type=rt>>5, r0=(rt&31)*128) x one
// col-group (g=blockIdx.x: 512 logical cols, h2 = g>=CG/2 selects own-matrix
// half with masked diagonal).
// A fragments: K=128 register-resident (af[4][4], loaded once from L2-hot ab).
// B: 64-col x K128 tiles (16 KB) double-buffered in LDS, global_load_lds
// prefetch of it+1 before computing it; barrier at iter end drains vmcnt.
// XOR-octet swizzle: LDS granule (row,g) holds global octet g^(row&15) so the
// DMA dest is lane-contiguous and ds_read_b128 is ~conflict-free.
// Waves 2x2 over 128x64: wave tile 64 rows x 32 cols, 32 MFMAs/iter.
// WRITE=false: per-lane partial rowsums in regs, one atomic flush at end.
// WRITE=true : out = exp2(K2*acc + c_row), c_row = -log2(sum) - K2.
// ---------------------------------------------------------------------------
template <bool WRITE>
__global__ __launch_bounds__(256, 2) void pass_kernel(const f16* __restrict__ ab,
                                                      float* __restrict__ rowsum,
                                                      float* __restrict__ out) {
  __shared__ f16 Bs[2][64 * ND];   // 2 x 16 KB
  __shared__ float cs[128];

  const int t    = threadIdx.x;
  const int wave = t >> 6;
  const int lane = t & 63;
  const int wr   = wave >> 1;
  const int wc   = wave & 1;
  const int quad = lane >> 4;
  const int l16  = lane & 15;

  const int rt    = blockIdx.y;            // 0..63
  const int type  = rt >> 5;               // 0 = part1 (query a), 1 = part2 (b)
  const int r0    = (rt & 31) * 128;       // query row base in [0,4096)
  const int g     = blockIdx.x;            // 0..CG-1
  const int h2    = (g >= CG / 2) ? 1 : 0; // own-matrix half (diag masked)
  const int cbl   = g * (8192 / CG);       // logical col base (0..8191)
  const int cbase = cbl & (NB - 1);        // within-matrix col base
  const f16* Q  = ab + (size_t)type * NB * ND;
  const f16* Kp = ab + (size_t)(h2 ? type : (type ^ 1)) * NB * ND;

  // ---- A fragments: K=128 fully in registers, straight from global (L2-hot).
  // 16x16x32 A-layout: lane(q,l) holds A[row=l][k=ks*32+q*8 .. +7] -> 16B load.
  f16x8 af[4][4];
  {
    const int arow = r0 + wr * 64 + l16;
#pragma unroll
    for (int mi = 0; mi < 4; ++mi)
#pragma unroll
      for (int ks = 0; ks < 4; ++ks)
        af[mi][ks] = *(const f16x8*)(Q + (size_t)(arow + mi * 16) * ND +
                                     ks * 32 + quad * 8);
  }

  // ---- B tile staging: 64 rows x 128 K, 4 global_load_lds x 16B per thread.
  const int sub = t >> 4;   // 0..15
  const int oct = t & 15;
  auto stage_b = [&](f16* buf, int kc0) {
#pragma unroll
    for (int i = 0; i < 4; ++i) {
      int rowl = i * 16 + sub;
      int goct = oct ^ (rowl & 15);
      __builtin_amdgcn_global_load_lds(
          (const __attribute__((address_space(1))) void*)(
              Kp + (size_t)(kc0 + rowl) * ND + goct * 8),
          (__attribute__((address_space(3))) void*)(buf + rowl * ND + oct * 8),
          16, 0, 0);
    }
  };

  float ps[4][4];
  if (!WRITE) {
#pragma unroll
    for (int mi = 0; mi < 4; ++mi)
#pragma unroll
      for (int r = 0; r < 4; ++r) ps[mi][r] = 0.0f;
  }

  stage_b(Bs[0], cbase);
  if (WRITE) {
    if (t < 128) cs[t] = -__log2f(rowsum[rt * 128 + t]) - K2;
  }
  __syncthreads();

  for (int it = 0; it < IT; ++it) {
    if (it + 1 < IT) stage_b(Bs[(it + 1) & 1], cbase + (it + 1) * 64);

    const f16* buf = Bs[it & 1];
    f32x4 acc[4][2] = {};
#pragma unroll
    for (int ks = 0; ks < 4; ++ks) {
      int sw = (((ks * 4 + quad) ^ l16)) * 8;
      f16x8 bf0 = *(const f16x8*)(buf + (wc * 32 + l16) * ND + sw);
      f16x8 bf1 = *(const f16x8*)(buf + (wc * 32 + 16 + l16) * ND + sw);
#pragma unroll
      for (int mi = 0; mi < 4; ++mi) {
        acc[mi][0] = __builtin_amdgcn_mfma_f32_16x16x32_f16(af[mi][ks], bf0,
                                                            acc[mi][0], 0, 0, 0);
        acc[mi][1] = __builtin_amdgcn_mfma_f32_16x16x32_f16(af[mi][ks], bf1,
                                                            acc[mi][1], 0, 0, 0);
      }
    }

    const int c0m = cbase + it * 64;                 // within-matrix col base
    const bool dtile = h2 && (c0m == r0 || c0m == r0 + 64);

    if (WRITE) {
      float4 cf[4];
#pragma unroll
      for (int mi = 0; mi < 4; ++mi)
        cf[mi] = *(const float4*)&cs[wr * 64 + mi * 16 + quad * 4];
#pragma unroll
      for (int mi = 0; mi < 4; ++mi) {
        const float* cp = &cf[mi].x;
#pragma unroll
        for (int ni = 0; ni < 2; ++ni) {
          int col_l = wc * 32 + ni * 16 + l16;
          size_t cout = (size_t)type * 8192 + cbl + it * 64 + col_l;
#pragma unroll
          for (int r = 0; r < 4; ++r) {
            int row_l = wr * 64 + mi * 16 + quad * 4 + r;
            float e = __builtin_amdgcn_exp2f(fmaf(acc[mi][ni][r], K2, cp[r]));
            if (dtile && (c0m + col_l == r0 + row_l)) e = 0.0f;
            out[(size_t)(r0 + row_l) * OUTW + cout] = e;
          }
        }
      }
    } else {
#pragma unroll
      for (int mi = 0; mi < 4; ++mi) {
#pragma unroll
        for (int ni = 0; ni < 2; ++ni) {
          int col_l = wc * 32 + ni * 16 + l16;
#pragma unroll
          for (int r = 0; r < 4; ++r) {
            int row_l = wr * 64 + mi * 16 + quad * 4 + r;
            float e = __builtin_amdgcn_exp2f(fmaf(acc[mi][ni][r], K2, -K2));
            if (dtile && (c0m + col_l == r0 + row_l)) e = 0.0f;
            ps[mi][r] += e;
          }
        }
      }
    }
    __syncthreads();
  }

  if (!WRITE) {
    // reduce each ps over the 16 cols (l16) and flush: 2 atomics/row/block.
#pragma unroll
    for (int mi = 0; mi < 4; ++mi)
#pragma unroll
      for (int r = 0; r < 4; ++r) {
        float v = ps[mi][r];
#pragma unroll
        for (int off = 1; off < 16; off <<= 1) v += __shfl_xor(v, off);
        if (l16 == 0) {
          int row_l = wr * 64 + mi * 16 + quad * 4 + r;
          atomicAdd(&rowsum[rt * 128 + row_l], v);
        }
      }
  }
}

// ---------------------------------------------------------------------------
extern "C" void kernel_launch(void* const* d_in, const int* in_sizes, int n_in,
                              void* d_out, int out_size, void* d_ws, size_t ws_size,
                              hipStream_t stream) {
  const float* z1 = (const float*)d_in[0];
  const float* z2 = (const float*)d_in[1];
  float* out = (float*)d_out;

  f16* ab = (f16*)d_ws;                                   // 8192x128 f16 = 2 MB
  float* rowsum = (float*)((char*)d_ws + (size_t)8192 * ND * sizeof(f16)); // 32 KB

  nrm_kernel<<<2048, 256, 0, stream>>>(z1, z2, ab, rowsum);
  dim3 grid(CG, 64);
  pass_kernel<false><<<grid, 256, 0, stream>>>(ab, rowsum, out);
  pass_kernel<true><<<grid, 256, 0, stream>>>(ab, rowsum, out);
}